// Round 3
// baseline (283.221 us; speedup 1.0000x reference)
//
#include <hip/hip_runtime.h>

typedef _Float16 f16;
typedef f16 f16x2 __attribute__((ext_vector_type(2)));
typedef f16 f16x4 __attribute__((ext_vector_type(4)));
typedef f16 f16x8 __attribute__((ext_vector_type(8)));
typedef float f32x4 __attribute__((ext_vector_type(4)));

#define NB 4
#define NS 2048
#define ND 1024
#define NH 16
#define NDH 64

__device__ __forceinline__ void gl2lds16(const void* g, void* l) {
  __builtin_amdgcn_global_load_lds(
      (const __attribute__((address_space(1))) unsigned int*)g,
      (__attribute__((address_space(3))) unsigned int*)l, 16, 0, 0);
}

__device__ __forceinline__ float fast_exp2(float x) {
  return __builtin_amdgcn_exp2f(x);  // v_exp_f32
}

__device__ __forceinline__ f16x2 pk_f16(float a, float b) {
  return __builtin_bit_cast(f16x2, __builtin_amdgcn_cvt_pkrtz(a, b));  // v_cvt_pkrtz_f16_f32
}

// ---------------- fp32 -> f16 conversion (all 4 inputs, one launch) ----------
__global__ __launch_bounds__(256) void cvt_all(
    const float* __restrict__ X, const float* __restrict__ Wq,
    const float* __restrict__ Wk, const float* __restrict__ Wv,
    f16* __restrict__ Xh, f16* __restrict__ Wh) {
  int b = blockIdx.x;
  const float* src;
  f16* dst;
  int off;
  if (b < 8192)       { src = X;  dst = Xh;               off = 0; }
  else if (b < 9216)  { src = Wq; dst = Wh;               off = 8192; }
  else if (b < 10240) { src = Wk; dst = Wh + (1u << 20);  off = 9216; }
  else                { src = Wv; dst = Wh + (2u << 20);  off = 10240; }
  int i = (b - off) * 256 + threadIdx.x;
  float4 v = ((const float4*)src)[i];
  f16x4 h = {(f16)v.x, (f16)v.y, (f16)v.z, (f16)v.w};
  ((f16x4*)dst)[i] = h;
}

// ---------------- fused QKV projection GEMM ----------------
// BK=64, single-buffered LDS with XOR-swizzled staging (see comments in loop).
// QF/KF stored in K=32 MFMA fragment order (coalesced 16B/lane in attn):
//   frag f covers dh f*32..f*32+31 of a 16-row tile; lane L holds
//   M[row = tile*16 + (L&15)][dh = f*32 + (L>>4)*8 + j], j=0..7 (16B).
//   Address: (((bh*128+tile)*2+f)*64+L)*8 + j.   Q pre-scaled by 1/8*log2(e).
// VF stored in K=32 PV B-frag order over 32-key groups (kt2 = key>>5):
//   lane (quad,lr), slot j:  key = 32*kt2 + (j<4 ? quad*4+j : 16+quad*4+(j-4)),
//   dh = dt*16+lr.  addr = ((bh*64+kt2)*4+dt)*512 + lane*8 + j.
//   (k-slot<->key mapping is a free bijection; chosen so attn's P A-frag is
//   the raw concatenation of the two 16-key exp results -> zero shuffles.)
__global__ __launch_bounds__(256) void qkv_gemm(
    const f16* __restrict__ Xh, const f16* __restrict__ Wh,
    const float* __restrict__ bq, const float* __restrict__ bk,
    const float* __restrict__ bv,
    f16* __restrict__ QF, f16* __restrict__ KF, f16* __restrict__ VF) {
  __shared__ f16 Ah[128 * 64];
  __shared__ f16 Bh[128 * 64];
  const int t = threadIdx.x;
  const int tileM = blockIdx.x * 128;
  const int nGlob = blockIdx.y * 128;
  const int mat = nGlob >> 10;
  const int col0 = nGlob & 1023;
  const int wave = t >> 6, lane = t & 63;
  const int mOff = (wave & 1) * 64, nOff = (wave >> 1) * 64;
  const int lr = lane & 15, quad = lane >> 4;

  f32x4 acc[4][4];
#pragma unroll
  for (int i = 0; i < 4; i++)
#pragma unroll
    for (int j = 0; j < 4; j++) acc[i][j] = f32x4{0.f, 0.f, 0.f, 0.f};

  // staging: thread t owns phys (row = t>>3, chunk = t&7); source chunk is
  // swizzled so that phys chunk p of row r holds logical chunk p^(r&7).
  const int srow = t >> 3;                        // 0..31
  const int sx = ((t & 7) ^ (srow & 7)) * 8;      // f16 offset within row
  const f16* ag = Xh + (size_t)(tileM + srow) * ND + sx;
  const f16* bg = Wh + (size_t)mat * ND * ND + (size_t)(col0 + srow) * ND + sx;
  const bool qk = (mat < 2);
  const int rx = lr & 7;  // row&7 for all frag rows this lane reads

  for (int kk = 0; kk < ND; kk += 64) {
    __syncthreads();
    gl2lds16(ag + kk,                       Ah + t * 8);
    gl2lds16(ag + (size_t)32 * ND + kk,     Ah + 2048 + t * 8);
    gl2lds16(ag + (size_t)64 * ND + kk,     Ah + 4096 + t * 8);
    gl2lds16(ag + (size_t)96 * ND + kk,     Ah + 6144 + t * 8);
    gl2lds16(bg + kk,                       Bh + t * 8);
    gl2lds16(bg + (size_t)32 * ND + kk,     Bh + 2048 + t * 8);
    gl2lds16(bg + (size_t)64 * ND + kk,     Bh + 4096 + t * 8);
    gl2lds16(bg + (size_t)96 * ND + kk,     Bh + 6144 + t * 8);
    __syncthreads();
#pragma unroll
    for (int c = 0; c < 2; c++) {
      const int ch = ((c * 4 + quad) ^ rx) * 8;  // swizzled chunk (f16 units)
      f16x8 af[4], bf[4];
#pragma unroll
      for (int i = 0; i < 4; i++)
        af[i] = *(const f16x8*)(Ah + (mOff + i * 16 + lr) * 64 + ch);
#pragma unroll
      for (int j = 0; j < 4; j++)
        bf[j] = *(const f16x8*)(Bh + (nOff + j * 16 + lr) * 64 + ch);
      if (qk) {
#pragma unroll
        for (int i = 0; i < 4; i++)
#pragma unroll
          for (int j = 0; j < 4; j++)
            acc[i][j] = __builtin_amdgcn_mfma_f32_16x16x32_f16(bf[j], af[i], acc[i][j], 0, 0, 0);
      } else {
#pragma unroll
        for (int i = 0; i < 4; i++)
#pragma unroll
          for (int j = 0; j < 4; j++)
            acc[i][j] = __builtin_amdgcn_mfma_f32_16x16x32_f16(af[i], bf[j], acc[i][j], 0, 0, 0);
      }
    }
  }

  if (qk) {
    // acc[i][j][r] = C[dh_n = col0+nOff+j*16+quad*4+r][row = tileM+mOff+i*16+lr]
    // Target: frag f=j>>1, lane lam=lr+16*((2j+(quad>>1))&3), byte jstart=(quad&1)*4.
    const float* bias = (mat == 0) ? bq : bk;
    f16* dst = (mat == 0) ? QF : KF;
    const float sc = (mat == 0) ? 0.18033688f : 1.0f;  // 1/8*log2(e) folded into Q
    const int jstart = (quad & 1) * 4;
#pragma unroll
    for (int j = 0; j < 4; j++) {
      int n0 = col0 + nOff + j * 16;
      int h = n0 >> 6;
      int f = j >> 1;
      int lam = lr + 16 * ((2 * j + (quad >> 1)) & 3);
      float4 bb = *(const float4*)(bias + n0 + quad * 4);
#pragma unroll
      for (int i = 0; i < 4; i++) {
        int sF = tileM + mOff + i * 16;
        int b = sF >> 11, st = (sF & 2047) >> 4;
        int bh = b * NH + h;
        f16x4 v;
#pragma unroll
        for (int r = 0; r < 4; r++) v[r] = (f16)((acc[i][j][r] + (&bb.x)[r]) * sc);
        *(f16x4*)(dst + (((size_t)(bh * 128 + st) * 2 + f) * 64 + lam) * 8 + jstart) = v;
      }
    }
  } else {
    // acc[i][j][r] = C[key = tileM+mOff+i*16+quad*4+r][dh_n = col0+nOff+j*16+lr]
    // K=32 B-frag layout: lane's 4 values land at slots j' = 4*(tile&1)+r
    // of target lane (quad*16+lr) in group kt2 = key>>5.
#pragma unroll
    for (int j = 0; j < 4; j++) {
      int n = col0 + nOff + j * 16 + lr;
      int h = n >> 6, dt = (n >> 4) & 3;
      float bb = bv[n];
#pragma unroll
      for (int i = 0; i < 4; i++) {
        int sF = tileM + mOff + i * 16;
        int b = sF >> 11;
        int kt2 = (sF & 2047) >> 5;
        int ts = (sF >> 4) & 1;
        int bh = b * NH + h;
        f16x4 v;
#pragma unroll
        for (int r = 0; r < 4; r++) v[r] = (f16)(acc[i][j][r] + bb);
        *(f16x4*)(VF + ((size_t)(bh * 64 + kt2) * 4 + dt) * 512 +
                  (size_t)(quad * 16 + lr) * 8 + 4 * ts) = v;
      }
    }
  }
}

// ---------------- flash attention: zero LDS, zero barriers ----------------
// 512-thread blocks, 8 waves, wave owns ONE 16-row q tile.  grid (64,16) =
// 1024 blocks -> up to 4 blocks/CU; __launch_bounds__(512,6) caps VGPR at ~85
// so 3 blocks/CU (6 waves/SIMD, 75% occ) are resident vs 39% before — the
// kernel was chain-latency-bound (MfmaUtil 41 / VALUBusy 38, both unsaturated).
// Per 32-key group: 4 QK + 4 PV + 1 lacc MFMA (all 16x16x32).  K prefetched
// in-place under exp+PV; V load issued under next QK.  All MFMA K=32; P
// A-frag = raw concat of the two 16-key exp results (zero shuffles).
// grid x = bh -> xcd = bh&7: all 16 q-blocks of one bh share one XCD's L2.
__global__ __launch_bounds__(512, 6) void attn_kernel(
    const f16* __restrict__ QF, const f16* __restrict__ KF,
    const f16* __restrict__ VF, float* __restrict__ out) {
  const int t = threadIdx.x, wave = t >> 6, lane = t & 63;
  const int lr = lane & 15, quad = lane >> 4;
  const int bh = blockIdx.x, qb = blockIdx.y;
  const int bb = bh >> 4, hh = bh & 15;
  const size_t bhOff = (size_t)bh * 131072;  // 128 tiles * 2 frags * 512
  const f16* Qp = QF + bhOff + (size_t)lane * 8;
  const f16* Kp = KF + bhOff + (size_t)lane * 8;
  const f16* Vp = VF + bhOff + (size_t)lane * 8;
  const int st = qb * 8 + wave;  // q tile 0..127

  // Q B-frags for K=32 (n=q=lane&15, k=dh=(lane>>4)*8+j + f*32), pre-scaled
  f16x8 qf0 = *(const f16x8*)(Qp + (size_t)st * 1024);
  f16x8 qf1 = *(const f16x8*)(Qp + (size_t)st * 1024 + 512);

  f32x4 o[4];
#pragma unroll
  for (int dt = 0; dt < 4; dt++) o[dt] = f32x4{0.f, 0.f, 0.f, 0.f};
  f32x4 lacc = f32x4{0.f, 0.f, 0.f, 0.f};
  const f16x8 ones8 = {(f16)1.f, (f16)1.f, (f16)1.f, (f16)1.f,
                       (f16)1.f, (f16)1.f, (f16)1.f, (f16)1.f};

  // K: tiles 2*kt2, 2*kt2+1 at offsets kt2*2048 + {0,512,1024,1536}
  // V: group kt2 at offsets kt2*2048 + dt*512
  f16x8 kk[4], vv[4];
#pragma unroll
  for (int i = 0; i < 4; i++) kk[i] = *(const f16x8*)(Kp + i * 512);
#pragma unroll
  for (int i = 0; i < 4; i++) vv[i] = *(const f16x8*)(Vp + i * 512);

  for (int kt2 = 0; kt2 < 64; ++kt2) {
    // ---- QK^T: two 16-key tiles, K=32 over dh ----
    f32x4 sA = f32x4{0.f, 0.f, 0.f, 0.f};
    f32x4 sB = f32x4{0.f, 0.f, 0.f, 0.f};
    sA = __builtin_amdgcn_mfma_f32_16x16x32_f16(kk[0], qf0, sA, 0, 0, 0);
    sA = __builtin_amdgcn_mfma_f32_16x16x32_f16(kk[1], qf1, sA, 0, 0, 0);
    sB = __builtin_amdgcn_mfma_f32_16x16x32_f16(kk[2], qf0, sB, 0, 0, 0);
    sB = __builtin_amdgcn_mfma_f32_16x16x32_f16(kk[3], qf1, sB, 0, 0, 0);
    // kk free -> prefetch next group's K in place (covered by exp+PV)
    const size_t nk = (size_t)((kt2 + 1) & 63) * 2048;
#pragma unroll
    for (int i = 0; i < 4; i++) kk[i] = *(const f16x8*)(Kp + nk + i * 512);
    // ---- exp -> P A-frag (K=32): [expA(4), expB(4)], no shuffles ----
    f16x2 a0 = pk_f16(fast_exp2(sA[0]), fast_exp2(sA[1]));
    f16x2 a1 = pk_f16(fast_exp2(sA[2]), fast_exp2(sA[3]));
    f16x2 b0 = pk_f16(fast_exp2(sB[0]), fast_exp2(sB[1]));
    f16x2 b1 = pk_f16(fast_exp2(sB[2]), fast_exp2(sB[3]));
    f16x4 lo = __builtin_shufflevector(a0, a1, 0, 1, 2, 3);
    f16x4 hi = __builtin_shufflevector(b0, b1, 0, 1, 2, 3);
    f16x8 pf = __builtin_shufflevector(lo, hi, 0, 1, 2, 3, 4, 5, 6, 7);
    // ---- PV + denominator, all K=32 ----
#pragma unroll
    for (int dt = 0; dt < 4; dt++)
      o[dt] = __builtin_amdgcn_mfma_f32_16x16x32_f16(pf, vv[dt], o[dt], 0, 0, 0);
    lacc = __builtin_amdgcn_mfma_f32_16x16x32_f16(pf, ones8, lacc, 0, 0, 0);
    // vv free -> prefetch next group's V in place (covered by next QK+exp)
#pragma unroll
    for (int i = 0; i < 4; i++) vv[i] = *(const f16x8*)(Vp + nk + i * 512);
  }

  // lacc C-layout: lane holds q=quad*4+r (all cols equal) -> no shuffles
#pragma unroll
  for (int r = 0; r < 4; r++) {
    float inv = 1.0f / lacc[r];
    int q = qb * 128 + wave * 16 + quad * 4 + r;
#pragma unroll
    for (int dt = 0; dt < 4; dt++)
      out[((size_t)bb * NS + q) * ND + hh * 64 + dt * 16 + lr] = o[dt][r] * inv;
  }
}

extern "C" void kernel_launch(void* const* d_in, const int* in_sizes, int n_in,
                              void* d_out, int out_size, void* d_ws, size_t ws_size,
                              hipStream_t stream) {
  const float* X  = (const float*)d_in[0];
  const float* Wq = (const float*)d_in[1];
  const float* bq = (const float*)d_in[2];
  const float* Wk = (const float*)d_in[3];
  const float* bk = (const float*)d_in[4];
  const float* Wv = (const float*)d_in[5];
  const float* bv = (const float*)d_in[6];
  float* out = (float*)d_out;

  // ws: Xh 16MB | Wh 6MB | QF 16MB | KF 16MB | VF 16MB = 70MB
  f16* Xh = (f16*)d_ws;
  f16* Wh = (f16*)((char*)d_ws + (size_t)(16u << 20));
  f16* QF = (f16*)((char*)d_ws + (size_t)(22u << 20));
  f16* KF = (f16*)((char*)d_ws + (size_t)(38u << 20));
  f16* VF = (f16*)((char*)d_ws + (size_t)(54u << 20));

  cvt_all<<<11264, 256, 0, stream>>>(X, Wq, Wk, Wv, Xh, Wh);
  qkv_gemm<<<dim3(64, 24), 256, 0, stream>>>(Xh, Wh, bq, bk, bv, QF, KF, VF);
  attn_kernel<<<dim3(64, 16), 512, 0, stream>>>(QF, KF, VF, out);
}

// Round 4
// 218.234 us; speedup vs baseline: 1.2978x; 1.2978x over previous
//
#include <hip/hip_runtime.h>

typedef _Float16 f16;
typedef f16 f16x2 __attribute__((ext_vector_type(2)));
typedef f16 f16x4 __attribute__((ext_vector_type(4)));
typedef f16 f16x8 __attribute__((ext_vector_type(8)));
typedef float f32x4 __attribute__((ext_vector_type(4)));

#define NB 4
#define NS 2048
#define ND 1024
#define NH 16
#define NDH 64

__device__ __forceinline__ void gl2lds16(const void* g, void* l) {
  __builtin_amdgcn_global_load_lds(
      (const __attribute__((address_space(1))) unsigned int*)g,
      (__attribute__((address_space(3))) unsigned int*)l, 16, 0, 0);
}

__device__ __forceinline__ float fast_exp2(float x) {
  return __builtin_amdgcn_exp2f(x);  // v_exp_f32
}

__device__ __forceinline__ f16x2 pk_f16(float a, float b) {
  return __builtin_bit_cast(f16x2, __builtin_amdgcn_cvt_pkrtz(a, b));  // v_cvt_pkrtz_f16_f32
}

// ---------------- fp32 -> f16 conversion (all 4 inputs, one launch) ----------
__global__ __launch_bounds__(256) void cvt_all(
    const float* __restrict__ X, const float* __restrict__ Wq,
    const float* __restrict__ Wk, const float* __restrict__ Wv,
    f16* __restrict__ Xh, f16* __restrict__ Wh) {
  int b = blockIdx.x;
  const float* src;
  f16* dst;
  int off;
  if (b < 8192)       { src = X;  dst = Xh;               off = 0; }
  else if (b < 9216)  { src = Wq; dst = Wh;               off = 8192; }
  else if (b < 10240) { src = Wk; dst = Wh + (1u << 20);  off = 9216; }
  else                { src = Wv; dst = Wh + (2u << 20);  off = 10240; }
  int i = (b - off) * 256 + threadIdx.x;
  float4 v = ((const float4*)src)[i];
  f16x4 h = {(f16)v.x, (f16)v.y, (f16)v.z, (f16)v.w};
  ((f16x4*)dst)[i] = h;
}

// ---------------- fused QKV projection GEMM ----------------
// BK=64, single-buffered LDS with XOR-swizzled staging (see comments in loop).
// QF/KF stored in K=32 MFMA fragment order (coalesced 16B/lane in attn):
//   frag f covers dh f*32..f*32+31 of a 16-row tile; lane L holds
//   M[row = tile*16 + (L&15)][dh = f*32 + (L>>4)*8 + j], j=0..7 (16B).
//   Address: (((bh*128+tile)*2+f)*64+L)*8 + j.   Q pre-scaled by 1/8*log2(e).
// VF stored in K=32 PV B-frag order over 32-key groups (kt2 = key>>5):
//   lane (quad,lr), slot j:  key = 32*kt2 + (j<4 ? quad*4+j : 16+quad*4+(j-4)),
//   dh = dt*16+lr.  addr = ((bh*64+kt2)*4+dt)*512 + lane*8 + j.
//   (k-slot<->key mapping is a free bijection; chosen so attn's P A-frag is
//   the raw concatenation of the two 16-key exp results -> zero shuffles.)
__global__ __launch_bounds__(256) void qkv_gemm(
    const f16* __restrict__ Xh, const f16* __restrict__ Wh,
    const float* __restrict__ bq, const float* __restrict__ bk,
    const float* __restrict__ bv,
    f16* __restrict__ QF, f16* __restrict__ KF, f16* __restrict__ VF) {
  __shared__ f16 Ah[128 * 64];
  __shared__ f16 Bh[128 * 64];
  const int t = threadIdx.x;
  const int tileM = blockIdx.x * 128;
  const int nGlob = blockIdx.y * 128;
  const int mat = nGlob >> 10;
  const int col0 = nGlob & 1023;
  const int wave = t >> 6, lane = t & 63;
  const int mOff = (wave & 1) * 64, nOff = (wave >> 1) * 64;
  const int lr = lane & 15, quad = lane >> 4;

  f32x4 acc[4][4];
#pragma unroll
  for (int i = 0; i < 4; i++)
#pragma unroll
    for (int j = 0; j < 4; j++) acc[i][j] = f32x4{0.f, 0.f, 0.f, 0.f};

  // staging: thread t owns phys (row = t>>3, chunk = t&7); source chunk is
  // swizzled so that phys chunk p of row r holds logical chunk p^(r&7).
  const int srow = t >> 3;                        // 0..31
  const int sx = ((t & 7) ^ (srow & 7)) * 8;      // f16 offset within row
  const f16* ag = Xh + (size_t)(tileM + srow) * ND + sx;
  const f16* bg = Wh + (size_t)mat * ND * ND + (size_t)(col0 + srow) * ND + sx;
  const bool qk = (mat < 2);
  const int rx = lr & 7;  // row&7 for all frag rows this lane reads

  for (int kk = 0; kk < ND; kk += 64) {
    __syncthreads();
    gl2lds16(ag + kk,                       Ah + t * 8);
    gl2lds16(ag + (size_t)32 * ND + kk,     Ah + 2048 + t * 8);
    gl2lds16(ag + (size_t)64 * ND + kk,     Ah + 4096 + t * 8);
    gl2lds16(ag + (size_t)96 * ND + kk,     Ah + 6144 + t * 8);
    gl2lds16(bg + kk,                       Bh + t * 8);
    gl2lds16(bg + (size_t)32 * ND + kk,     Bh + 2048 + t * 8);
    gl2lds16(bg + (size_t)64 * ND + kk,     Bh + 4096 + t * 8);
    gl2lds16(bg + (size_t)96 * ND + kk,     Bh + 6144 + t * 8);
    __syncthreads();
#pragma unroll
    for (int c = 0; c < 2; c++) {
      const int ch = ((c * 4 + quad) ^ rx) * 8;  // swizzled chunk (f16 units)
      f16x8 af[4], bf[4];
#pragma unroll
      for (int i = 0; i < 4; i++)
        af[i] = *(const f16x8*)(Ah + (mOff + i * 16 + lr) * 64 + ch);
#pragma unroll
      for (int j = 0; j < 4; j++)
        bf[j] = *(const f16x8*)(Bh + (nOff + j * 16 + lr) * 64 + ch);
      if (qk) {
#pragma unroll
        for (int i = 0; i < 4; i++)
#pragma unroll
          for (int j = 0; j < 4; j++)
            acc[i][j] = __builtin_amdgcn_mfma_f32_16x16x32_f16(bf[j], af[i], acc[i][j], 0, 0, 0);
      } else {
#pragma unroll
        for (int i = 0; i < 4; i++)
#pragma unroll
          for (int j = 0; j < 4; j++)
            acc[i][j] = __builtin_amdgcn_mfma_f32_16x16x32_f16(af[i], bf[j], acc[i][j], 0, 0, 0);
      }
    }
  }

  if (qk) {
    // acc[i][j][r] = C[dh_n = col0+nOff+j*16+quad*4+r][row = tileM+mOff+i*16+lr]
    // Target: frag f=j>>1, lane lam=lr+16*((2j+(quad>>1))&3), byte jstart=(quad&1)*4.
    const float* bias = (mat == 0) ? bq : bk;
    f16* dst = (mat == 0) ? QF : KF;
    const float sc = (mat == 0) ? 0.18033688f : 1.0f;  // 1/8*log2(e) folded into Q
    const int jstart = (quad & 1) * 4;
#pragma unroll
    for (int j = 0; j < 4; j++) {
      int n0 = col0 + nOff + j * 16;
      int h = n0 >> 6;
      int f = j >> 1;
      int lam = lr + 16 * ((2 * j + (quad >> 1)) & 3);
      float4 bb = *(const float4*)(bias + n0 + quad * 4);
#pragma unroll
      for (int i = 0; i < 4; i++) {
        int sF = tileM + mOff + i * 16;
        int b = sF >> 11, st = (sF & 2047) >> 4;
        int bh = b * NH + h;
        f16x4 v;
#pragma unroll
        for (int r = 0; r < 4; r++) v[r] = (f16)((acc[i][j][r] + (&bb.x)[r]) * sc);
        *(f16x4*)(dst + (((size_t)(bh * 128 + st) * 2 + f) * 64 + lam) * 8 + jstart) = v;
      }
    }
  } else {
    // acc[i][j][r] = C[key = tileM+mOff+i*16+quad*4+r][dh_n = col0+nOff+j*16+lr]
    // K=32 B-frag layout: lane's 4 values land at slots j' = 4*(tile&1)+r
    // of target lane (quad*16+lr) in group kt2 = key>>5.
#pragma unroll
    for (int j = 0; j < 4; j++) {
      int n = col0 + nOff + j * 16 + lr;
      int h = n >> 6, dt = (n >> 4) & 3;
      float bb = bv[n];
#pragma unroll
      for (int i = 0; i < 4; i++) {
        int sF = tileM + mOff + i * 16;
        int b = sF >> 11;
        int kt2 = (sF & 2047) >> 5;
        int ts = (sF >> 4) & 1;
        int bh = b * NH + h;
        f16x4 v;
#pragma unroll
        for (int r = 0; r < 4; r++) v[r] = (f16)(acc[i][j][r] + bb);
        *(f16x4*)(VF + ((size_t)(bh * 64 + kt2) * 4 + dt) * 512 +
                  (size_t)(quad * 16 + lr) * 8 + 4 * ts) = v;
      }
    }
  }
}

// ---------------- flash attention: LDS-shared K/V ----------------
// Round-3 post-mortem: per-wave K/V streaming is L1-BW-bound (traffic scales
// with wave count; 4.3 GB -> ~110 µs).  Fix: block of 8 waves (256 q, wave
// owns 32 q) stages each 32-key group's K (4 KB) + V (4 KB) into
// double-buffered LDS ONCE (global_load_lds, 1 instr/wave) and all waves
// ds_read fragments from LDS.  Global/L1 traffic drops 8x; K/V delivery
// moves to the LDS pipe (parallel to VMEM+MFMA).  2-phase schedule, one
// __syncthreads per group (staging is L2-resident, covered by ~18 MFMA).
// All MFMA K=32; P A-frag = raw concat of the two 16-key exp results.
// grid (64,8): xcd = bh&7 -> one bh's 8 q-blocks share one XCD's L2 (4 MB).
__global__ __launch_bounds__(512, 4) void attn_kernel(
    const f16* __restrict__ QF, const f16* __restrict__ KF,
    const f16* __restrict__ VF, float* __restrict__ out) {
  __shared__ f16 LK[2][2048];
  __shared__ f16 LV[2][2048];
  const int t = threadIdx.x, wave = t >> 6, lane = t & 63;
  const int lr = lane & 15, quad = lane >> 4;
  const int bh = blockIdx.x, qb = blockIdx.y;
  const int bb = bh >> 4, hh = bh & 15;
  const size_t bhOff = (size_t)bh * 131072;  // 256 KB of f16 per bh
  const f16* Qp = QF + bhOff + (size_t)lane * 8;
  const int st0 = qb * 16 + wave * 2;

  // staging source: threads 0..255 stage K group (4 KB), 256..511 stage V.
  // group kt2 lives at f16 offset kt2*2048 in both KF and VF.
  const int sidx = t & 255;
  const f16* sg = ((t < 256) ? KF : VF) + bhOff + (size_t)sidx * 8;

  // Q B-frags for K=32 (n=q=lane&15, k=dh=(lane>>4)*8+j + f*32), pre-scaled
  f16x8 qf[2][2];
#pragma unroll
  for (int qt = 0; qt < 2; qt++) {
    qf[qt][0] = *(const f16x8*)(Qp + (size_t)(st0 + qt) * 1024);
    qf[qt][1] = *(const f16x8*)(Qp + (size_t)(st0 + qt) * 1024 + 512);
  }

  f32x4 o[2][4];
#pragma unroll
  for (int qt = 0; qt < 2; qt++)
#pragma unroll
    for (int dt = 0; dt < 4; dt++) o[qt][dt] = f32x4{0.f, 0.f, 0.f, 0.f};
  f32x4 lacc[2];
#pragma unroll
  for (int qt = 0; qt < 2; qt++) lacc[qt] = f32x4{0.f, 0.f, 0.f, 0.f};
  const f16x8 ones8 = {(f16)1.f, (f16)1.f, (f16)1.f, (f16)1.f,
                       (f16)1.f, (f16)1.f, (f16)1.f, (f16)1.f};

  // prologue: stage group 0 into buffer 0
  {
    f16* dst = (t < 256) ? &LK[0][sidx * 8] : &LV[0][sidx * 8];
    gl2lds16(sg, dst);
  }
  __syncthreads();

  for (int kt2 = 0; kt2 < 64; ++kt2) {
    const int buf = kt2 & 1;
    // stage next group into the other buffer (in flight during compute)
    if (kt2 < 63) {
      f16* dst = (t < 256) ? &LK[buf ^ 1][sidx * 8] : &LV[buf ^ 1][sidx * 8];
      gl2lds16(sg + (size_t)(kt2 + 1) * 2048, dst);
    }
    // fragments from LDS (conflict-free linear b128)
    f16x8 kk[4], vv[4];
#pragma unroll
    for (int i = 0; i < 4; i++)
      kk[i] = *(const f16x8*)(&LK[buf][i * 512 + lane * 8]);
#pragma unroll
    for (int i = 0; i < 4; i++)
      vv[i] = *(const f16x8*)(&LV[buf][i * 512 + lane * 8]);
    // ---- QK^T: two 16-key tiles, K=32 over dh ----
    f32x4 sA[2], sB[2];
#pragma unroll
    for (int qt = 0; qt < 2; qt++) {
      sA[qt] = f32x4{0.f, 0.f, 0.f, 0.f};
      sA[qt] = __builtin_amdgcn_mfma_f32_16x16x32_f16(kk[0], qf[qt][0], sA[qt], 0, 0, 0);
      sA[qt] = __builtin_amdgcn_mfma_f32_16x16x32_f16(kk[1], qf[qt][1], sA[qt], 0, 0, 0);
      sB[qt] = f32x4{0.f, 0.f, 0.f, 0.f};
      sB[qt] = __builtin_amdgcn_mfma_f32_16x16x32_f16(kk[2], qf[qt][0], sB[qt], 0, 0, 0);
      sB[qt] = __builtin_amdgcn_mfma_f32_16x16x32_f16(kk[3], qf[qt][1], sB[qt], 0, 0, 0);
    }
    // ---- exp -> P A-frag (K=32): [expA(4), expB(4)] per qt, no shuffles ----
    f16x8 pf[2];
#pragma unroll
    for (int qt = 0; qt < 2; qt++) {
      f16x2 a0 = pk_f16(fast_exp2(sA[qt][0]), fast_exp2(sA[qt][1]));
      f16x2 a1 = pk_f16(fast_exp2(sA[qt][2]), fast_exp2(sA[qt][3]));
      f16x2 b0 = pk_f16(fast_exp2(sB[qt][0]), fast_exp2(sB[qt][1]));
      f16x2 b1 = pk_f16(fast_exp2(sB[qt][2]), fast_exp2(sB[qt][3]));
      f16x4 lo = __builtin_shufflevector(a0, a1, 0, 1, 2, 3);
      f16x4 hi = __builtin_shufflevector(b0, b1, 0, 1, 2, 3);
      pf[qt] = __builtin_shufflevector(lo, hi, 0, 1, 2, 3, 4, 5, 6, 7);
    }
    // ---- PV + denominator, all K=32 ----
#pragma unroll
    for (int dt = 0; dt < 4; dt++)
#pragma unroll
      for (int qt = 0; qt < 2; qt++)
        o[qt][dt] = __builtin_amdgcn_mfma_f32_16x16x32_f16(pf[qt], vv[dt], o[qt][dt], 0, 0, 0);
#pragma unroll
    for (int qt = 0; qt < 2; qt++)
      lacc[qt] = __builtin_amdgcn_mfma_f32_16x16x32_f16(pf[qt], ones8, lacc[qt], 0, 0, 0);
    // barrier: staging of next group complete + all waves done reading buf
    __syncthreads();
  }

  // lacc C-layout: lane holds q=quad*4+r (all cols equal) -> no shuffles
#pragma unroll
  for (int qt = 0; qt < 2; qt++) {
#pragma unroll
    for (int r = 0; r < 4; r++) {
      float inv = 1.0f / lacc[qt][r];
      int q = qb * 256 + wave * 32 + qt * 16 + quad * 4 + r;
#pragma unroll
      for (int dt = 0; dt < 4; dt++)
        out[((size_t)bb * NS + q) * ND + hh * 64 + dt * 16 + lr] = o[qt][dt][r] * inv;
    }
  }
}

extern "C" void kernel_launch(void* const* d_in, const int* in_sizes, int n_in,
                              void* d_out, int out_size, void* d_ws, size_t ws_size,
                              hipStream_t stream) {
  const float* X  = (const float*)d_in[0];
  const float* Wq = (const float*)d_in[1];
  const float* bq = (const float*)d_in[2];
  const float* Wk = (const float*)d_in[3];
  const float* bk = (const float*)d_in[4];
  const float* Wv = (const float*)d_in[5];
  const float* bv = (const float*)d_in[6];
  float* out = (float*)d_out;

  // ws: Xh 16MB | Wh 6MB | QF 16MB | KF 16MB | VF 16MB = 70MB
  f16* Xh = (f16*)d_ws;
  f16* Wh = (f16*)((char*)d_ws + (size_t)(16u << 20));
  f16* QF = (f16*)((char*)d_ws + (size_t)(22u << 20));
  f16* KF = (f16*)((char*)d_ws + (size_t)(38u << 20));
  f16* VF = (f16*)((char*)d_ws + (size_t)(54u << 20));

  cvt_all<<<11264, 256, 0, stream>>>(X, Wq, Wk, Wv, Xh, Wh);
  qkv_gemm<<<dim3(64, 24), 256, 0, stream>>>(Xh, Wh, bq, bk, bv, QF, KF, VF);
  attn_kernel<<<dim3(64, 8), 512, 0, stream>>>(QF, KF, VF, out);
}

// Round 5
// 217.565 us; speedup vs baseline: 1.3018x; 1.0031x over previous
//
#include <hip/hip_runtime.h>

typedef _Float16 f16;
typedef f16 f16x2 __attribute__((ext_vector_type(2)));
typedef f16 f16x4 __attribute__((ext_vector_type(4)));
typedef f16 f16x8 __attribute__((ext_vector_type(8)));
typedef float f32x4 __attribute__((ext_vector_type(4)));

#define NB 4
#define NS 2048
#define ND 1024
#define NH 16
#define NDH 64

__device__ __forceinline__ void gl2lds16(const void* g, void* l) {
  __builtin_amdgcn_global_load_lds(
      (const __attribute__((address_space(1))) unsigned int*)g,
      (__attribute__((address_space(3))) unsigned int*)l, 16, 0, 0);
}

__device__ __forceinline__ float fast_exp2(float x) {
  return __builtin_amdgcn_exp2f(x);  // v_exp_f32
}

__device__ __forceinline__ f16x2 pk_f16(float a, float b) {
  return __builtin_bit_cast(f16x2, __builtin_amdgcn_cvt_pkrtz(a, b));  // v_cvt_pkrtz_f16_f32
}

// ---------------- fp32 -> f16 conversion (all 4 inputs, one launch) ----------
__global__ __launch_bounds__(256) void cvt_all(
    const float* __restrict__ X, const float* __restrict__ Wq,
    const float* __restrict__ Wk, const float* __restrict__ Wv,
    f16* __restrict__ Xh, f16* __restrict__ Wh) {
  int b = blockIdx.x;
  const float* src;
  f16* dst;
  int off;
  if (b < 8192)       { src = X;  dst = Xh;               off = 0; }
  else if (b < 9216)  { src = Wq; dst = Wh;               off = 8192; }
  else if (b < 10240) { src = Wk; dst = Wh + (1u << 20);  off = 9216; }
  else                { src = Wv; dst = Wh + (2u << 20);  off = 10240; }
  int i = (b - off) * 256 + threadIdx.x;
  float4 v = ((const float4*)src)[i];
  f16x4 h = {(f16)v.x, (f16)v.y, (f16)v.z, (f16)v.w};
  ((f16x4*)dst)[i] = h;
}

// ---------------- fused QKV projection GEMM (unchanged) ----------------
// BK=64, single-buffered LDS with XOR-swizzled staging (see comments in loop).
// QF/KF stored in K=32 MFMA fragment order (coalesced 16B/lane in attn):
//   frag f covers dh f*32..f*32+31 of a 16-row tile; lane L holds
//   M[row = tile*16 + (L&15)][dh = f*32 + (L>>4)*8 + j], j=0..7 (16B).
//   Address: (((bh*128+tile)*2+f)*64+L)*8 + j.   Q pre-scaled by 1/8*log2(e).
// VF stored in K=32 PV B-frag order over 32-key groups (kt2 = key>>5):
//   lane (quad,lr), slot j:  key = 32*kt2 + (j<4 ? quad*4+j : 16+quad*4+(j-4)),
//   dh = dt*16+lr.  addr = ((bh*64+kt2)*4+dt)*512 + lane*8 + j.
__global__ __launch_bounds__(256) void qkv_gemm(
    const f16* __restrict__ Xh, const f16* __restrict__ Wh,
    const float* __restrict__ bq, const float* __restrict__ bk,
    const float* __restrict__ bv,
    f16* __restrict__ QF, f16* __restrict__ KF, f16* __restrict__ VF) {
  __shared__ f16 Ah[128 * 64];
  __shared__ f16 Bh[128 * 64];
  const int t = threadIdx.x;
  const int tileM = blockIdx.x * 128;
  const int nGlob = blockIdx.y * 128;
  const int mat = nGlob >> 10;
  const int col0 = nGlob & 1023;
  const int wave = t >> 6, lane = t & 63;
  const int mOff = (wave & 1) * 64, nOff = (wave >> 1) * 64;
  const int lr = lane & 15, quad = lane >> 4;

  f32x4 acc[4][4];
#pragma unroll
  for (int i = 0; i < 4; i++)
#pragma unroll
    for (int j = 0; j < 4; j++) acc[i][j] = f32x4{0.f, 0.f, 0.f, 0.f};

  const int srow = t >> 3;                        // 0..31
  const int sx = ((t & 7) ^ (srow & 7)) * 8;      // f16 offset within row
  const f16* ag = Xh + (size_t)(tileM + srow) * ND + sx;
  const f16* bg = Wh + (size_t)mat * ND * ND + (size_t)(col0 + srow) * ND + sx;
  const bool qk = (mat < 2);
  const int rx = lr & 7;  // row&7 for all frag rows this lane reads

  for (int kk = 0; kk < ND; kk += 64) {
    __syncthreads();
    gl2lds16(ag + kk,                       Ah + t * 8);
    gl2lds16(ag + (size_t)32 * ND + kk,     Ah + 2048 + t * 8);
    gl2lds16(ag + (size_t)64 * ND + kk,     Ah + 4096 + t * 8);
    gl2lds16(ag + (size_t)96 * ND + kk,     Ah + 6144 + t * 8);
    gl2lds16(bg + kk,                       Bh + t * 8);
    gl2lds16(bg + (size_t)32 * ND + kk,     Bh + 2048 + t * 8);
    gl2lds16(bg + (size_t)64 * ND + kk,     Bh + 4096 + t * 8);
    gl2lds16(bg + (size_t)96 * ND + kk,     Bh + 6144 + t * 8);
    __syncthreads();
#pragma unroll
    for (int c = 0; c < 2; c++) {
      const int ch = ((c * 4 + quad) ^ rx) * 8;  // swizzled chunk (f16 units)
      f16x8 af[4], bf[4];
#pragma unroll
      for (int i = 0; i < 4; i++)
        af[i] = *(const f16x8*)(Ah + (mOff + i * 16 + lr) * 64 + ch);
#pragma unroll
      for (int j = 0; j < 4; j++)
        bf[j] = *(const f16x8*)(Bh + (nOff + j * 16 + lr) * 64 + ch);
      if (qk) {
#pragma unroll
        for (int i = 0; i < 4; i++)
#pragma unroll
          for (int j = 0; j < 4; j++)
            acc[i][j] = __builtin_amdgcn_mfma_f32_16x16x32_f16(bf[j], af[i], acc[i][j], 0, 0, 0);
      } else {
#pragma unroll
        for (int i = 0; i < 4; i++)
#pragma unroll
          for (int j = 0; j < 4; j++)
            acc[i][j] = __builtin_amdgcn_mfma_f32_16x16x32_f16(af[i], bf[j], acc[i][j], 0, 0, 0);
      }
    }
  }

  if (qk) {
    const float* bias = (mat == 0) ? bq : bk;
    f16* dst = (mat == 0) ? QF : KF;
    const float sc = (mat == 0) ? 0.18033688f : 1.0f;  // 1/8*log2(e) folded into Q
    const int jstart = (quad & 1) * 4;
#pragma unroll
    for (int j = 0; j < 4; j++) {
      int n0 = col0 + nOff + j * 16;
      int h = n0 >> 6;
      int f = j >> 1;
      int lam = lr + 16 * ((2 * j + (quad >> 1)) & 3);
      float4 bb = *(const float4*)(bias + n0 + quad * 4);
#pragma unroll
      for (int i = 0; i < 4; i++) {
        int sF = tileM + mOff + i * 16;
        int b = sF >> 11, st = (sF & 2047) >> 4;
        int bh = b * NH + h;
        f16x4 v;
#pragma unroll
        for (int r = 0; r < 4; r++) v[r] = (f16)((acc[i][j][r] + (&bb.x)[r]) * sc);
        *(f16x4*)(dst + (((size_t)(bh * 128 + st) * 2 + f) * 64 + lam) * 8 + jstart) = v;
      }
    }
  } else {
#pragma unroll
    for (int j = 0; j < 4; j++) {
      int n = col0 + nOff + j * 16 + lr;
      int h = n >> 6, dt = (n >> 4) & 3;
      float bb = bv[n];
#pragma unroll
      for (int i = 0; i < 4; i++) {
        int sF = tileM + mOff + i * 16;
        int b = sF >> 11;
        int kt2 = (sF & 2047) >> 5;
        int ts = (sF >> 4) & 1;
        int bh = b * NH + h;
        f16x4 v;
#pragma unroll
        for (int r = 0; r < 4; r++) v[r] = (f16)(acc[i][j][r] + bb);
        *(f16x4*)(VF + ((size_t)(bh * 64 + kt2) * 4 + dt) * 512 +
                  (size_t)(quad * 16 + lr) * 8 + 4 * ts) = v;
      }
    }
  }
}

// ---------------- flash attention: LDS-shared K/V, 64 q per wave ----------
// R4 post-mortem: LDS-read pipe (2.1e6 ds_read_b128 x 12 cyc = 41 µs/CU agg)
// slightly exceeded the MFMA pipe (37 µs) — every one of 8 waves re-read the
// same 8 KB per group.  Fix: 4-wave blocks, each wave owns 64 q (4 qtiles) ->
// the same 8 ds_reads now feed 36 MFMA (2x FLOP per LDS byte); LDS pipe drops
// to ~20 µs, MFMA (37 µs) becomes the single dominant pipe.  grid (64,8) =
// 512 blocks = 2 INDEPENDENT blocks/CU (barrier-decoupled, unlike one 8-wave
// block) at 2 waves/SIMD (VGPR ~190 -> launch_bounds(256,2)).
// All MFMA K=32; P A-frag = raw concat of the two 16-key exp results.
// grid x = bh -> xcd = bh&7: one bh's q-blocks share one XCD's L2.
__global__ __launch_bounds__(256, 2) void attn_kernel(
    const f16* __restrict__ QF, const f16* __restrict__ KF,
    const f16* __restrict__ VF, float* __restrict__ out) {
  __shared__ f16 LK[2][2048];
  __shared__ f16 LV[2][2048];
  const int t = threadIdx.x, wave = t >> 6, lane = t & 63;
  const int lr = lane & 15, quad = lane >> 4;
  const int bh = blockIdx.x, qb = blockIdx.y;
  const int bb = bh >> 4, hh = bh & 15;
  const size_t bhOff = (size_t)bh * 131072;  // 256 KB of f16 per bh
  const f16* Qp = QF + bhOff + (size_t)lane * 8;
  const f16* Kg = KF + bhOff + (size_t)t * 8;  // staging: thread t -> 16B
  const f16* Vg = VF + bhOff + (size_t)t * 8;
  const int st0 = qb * 16 + wave * 4;  // first of 4 q-tiles for this wave

  // Q B-frags for K=32 (n=q=lane&15, k=dh=(lane>>4)*8+j + f*32), pre-scaled
  f16x8 qf[4][2];
#pragma unroll
  for (int qt = 0; qt < 4; qt++) {
    qf[qt][0] = *(const f16x8*)(Qp + (size_t)(st0 + qt) * 1024);
    qf[qt][1] = *(const f16x8*)(Qp + (size_t)(st0 + qt) * 1024 + 512);
  }

  f32x4 o[4][4];
#pragma unroll
  for (int qt = 0; qt < 4; qt++)
#pragma unroll
    for (int dt = 0; dt < 4; dt++) o[qt][dt] = f32x4{0.f, 0.f, 0.f, 0.f};
  f32x4 lacc[4];
#pragma unroll
  for (int qt = 0; qt < 4; qt++) lacc[qt] = f32x4{0.f, 0.f, 0.f, 0.f};
  const f16x8 ones8 = {(f16)1.f, (f16)1.f, (f16)1.f, (f16)1.f,
                       (f16)1.f, (f16)1.f, (f16)1.f, (f16)1.f};

  // prologue: stage group 0 into buffer 0 (K 4KB + V 4KB, 256 thr x 16B each)
  gl2lds16(Kg, &LK[0][t * 8]);
  gl2lds16(Vg, &LV[0][t * 8]);
  __syncthreads();

  for (int kt2 = 0; kt2 < 64; ++kt2) {
    const int buf = kt2 & 1;
    // stage next group (wrap) into the other buffer — in flight during compute
    const size_t nk = (size_t)((kt2 + 1) & 63) * 2048;
    gl2lds16(Kg + nk, &LK[buf ^ 1][t * 8]);
    gl2lds16(Vg + nk, &LV[buf ^ 1][t * 8]);
    // fragments from LDS (linear 16B/lane, conflict-free)
    f16x8 kk[4], vv[4];
#pragma unroll
    for (int i = 0; i < 4; i++)
      kk[i] = *(const f16x8*)(&LK[buf][i * 512 + lane * 8]);
#pragma unroll
    for (int i = 0; i < 4; i++)
      vv[i] = *(const f16x8*)(&LV[buf][i * 512 + lane * 8]);
    // ---- QK^T: two 16-key tiles per qt, K=32 over dh ----
    f32x4 sA[4], sB[4];
#pragma unroll
    for (int qt = 0; qt < 4; qt++) {
      sA[qt] = f32x4{0.f, 0.f, 0.f, 0.f};
      sA[qt] = __builtin_amdgcn_mfma_f32_16x16x32_f16(kk[0], qf[qt][0], sA[qt], 0, 0, 0);
      sA[qt] = __builtin_amdgcn_mfma_f32_16x16x32_f16(kk[1], qf[qt][1], sA[qt], 0, 0, 0);
      sB[qt] = f32x4{0.f, 0.f, 0.f, 0.f};
      sB[qt] = __builtin_amdgcn_mfma_f32_16x16x32_f16(kk[2], qf[qt][0], sB[qt], 0, 0, 0);
      sB[qt] = __builtin_amdgcn_mfma_f32_16x16x32_f16(kk[3], qf[qt][1], sB[qt], 0, 0, 0);
    }
    // ---- exp -> P A-frag (K=32): [expA(4), expB(4)] per qt, no shuffles ----
    f16x8 pf[4];
#pragma unroll
    for (int qt = 0; qt < 4; qt++) {
      f16x2 a0 = pk_f16(fast_exp2(sA[qt][0]), fast_exp2(sA[qt][1]));
      f16x2 a1 = pk_f16(fast_exp2(sA[qt][2]), fast_exp2(sA[qt][3]));
      f16x2 b0 = pk_f16(fast_exp2(sB[qt][0]), fast_exp2(sB[qt][1]));
      f16x2 b1 = pk_f16(fast_exp2(sB[qt][2]), fast_exp2(sB[qt][3]));
      f16x4 lo = __builtin_shufflevector(a0, a1, 0, 1, 2, 3);
      f16x4 hi = __builtin_shufflevector(b0, b1, 0, 1, 2, 3);
      pf[qt] = __builtin_shufflevector(lo, hi, 0, 1, 2, 3, 4, 5, 6, 7);
    }
    // ---- PV + denominator, all K=32 ----
#pragma unroll
    for (int dt = 0; dt < 4; dt++)
#pragma unroll
      for (int qt = 0; qt < 4; qt++)
        o[qt][dt] = __builtin_amdgcn_mfma_f32_16x16x32_f16(pf[qt], vv[dt], o[qt][dt], 0, 0, 0);
#pragma unroll
    for (int qt = 0; qt < 4; qt++)
      lacc[qt] = __builtin_amdgcn_mfma_f32_16x16x32_f16(pf[qt], ones8, lacc[qt], 0, 0, 0);
    // barrier: next-group staging complete + all waves done reading buf
    __syncthreads();
  }

  // lacc C-layout: lane holds q=quad*4+r (all cols equal) -> no shuffles
#pragma unroll
  for (int qt = 0; qt < 4; qt++) {
#pragma unroll
    for (int r = 0; r < 4; r++) {
      float inv = 1.0f / lacc[qt][r];
      int q = qb * 256 + wave * 64 + qt * 16 + quad * 4 + r;
#pragma unroll
      for (int dt = 0; dt < 4; dt++)
        out[((size_t)bb * NS + q) * ND + hh * 64 + dt * 16 + lr] = o[qt][dt][r] * inv;
    }
  }
}

extern "C" void kernel_launch(void* const* d_in, const int* in_sizes, int n_in,
                              void* d_out, int out_size, void* d_ws, size_t ws_size,
                              hipStream_t stream) {
  const float* X  = (const float*)d_in[0];
  const float* Wq = (const float*)d_in[1];
  const float* bq = (const float*)d_in[2];
  const float* Wk = (const float*)d_in[3];
  const float* bk = (const float*)d_in[4];
  const float* Wv = (const float*)d_in[5];
  const float* bv = (const float*)d_in[6];
  float* out = (float*)d_out;

  // ws: Xh 16MB | Wh 6MB | QF 16MB | KF 16MB | VF 16MB = 70MB
  f16* Xh = (f16*)d_ws;
  f16* Wh = (f16*)((char*)d_ws + (size_t)(16u << 20));
  f16* QF = (f16*)((char*)d_ws + (size_t)(22u << 20));
  f16* KF = (f16*)((char*)d_ws + (size_t)(38u << 20));
  f16* VF = (f16*)((char*)d_ws + (size_t)(54u << 20));

  cvt_all<<<11264, 256, 0, stream>>>(X, Wq, Wk, Wv, Xh, Wh);
  qkv_gemm<<<dim3(64, 24), 256, 0, stream>>>(Xh, Wh, bq, bk, bv, QF, KF, VF);
  attn_kernel<<<dim3(64, 8), 256, 0, stream>>>(QF, KF, VF, out);
}

// Round 6
// 215.957 us; speedup vs baseline: 1.3115x; 1.0074x over previous
//
#include <hip/hip_runtime.h>

typedef _Float16 f16;
typedef f16 f16x2 __attribute__((ext_vector_type(2)));
typedef f16 f16x4 __attribute__((ext_vector_type(4)));
typedef f16 f16x8 __attribute__((ext_vector_type(8)));
typedef float f32x4 __attribute__((ext_vector_type(4)));

#define NB 4
#define NS 2048
#define ND 1024
#define NH 16
#define NDH 64

__device__ __forceinline__ void gl2lds16(const void* g, void* l) {
  __builtin_amdgcn_global_load_lds(
      (const __attribute__((address_space(1))) unsigned int*)g,
      (__attribute__((address_space(3))) unsigned int*)l, 16, 0, 0);
}

__device__ __forceinline__ float fast_exp2(float x) {
  return __builtin_amdgcn_exp2f(x);  // v_exp_f32
}

__device__ __forceinline__ f16x2 pk_f16(float a, float b) {
  return __builtin_bit_cast(f16x2, __builtin_amdgcn_cvt_pkrtz(a, b));  // v_cvt_pkrtz_f16_f32
}

// ---------------- fp32 -> f16 conversion (all 4 inputs, one launch) ----------
__global__ __launch_bounds__(256) void cvt_all(
    const float* __restrict__ X, const float* __restrict__ Wq,
    const float* __restrict__ Wk, const float* __restrict__ Wv,
    f16* __restrict__ Xh, f16* __restrict__ Wh) {
  int b = blockIdx.x;
  const float* src;
  f16* dst;
  int off;
  if (b < 8192)       { src = X;  dst = Xh;               off = 0; }
  else if (b < 9216)  { src = Wq; dst = Wh;               off = 8192; }
  else if (b < 10240) { src = Wk; dst = Wh + (1u << 20);  off = 9216; }
  else                { src = Wv; dst = Wh + (2u << 20);  off = 10240; }
  int i = (b - off) * 256 + threadIdx.x;
  float4 v = ((const float4*)src)[i];
  f16x4 h = {(f16)v.x, (f16)v.y, (f16)v.z, (f16)v.w};
  ((f16x4*)dst)[i] = h;
}

// ---------------- fused QKV projection GEMM (unchanged) ----------------
// BK=64, single-buffered LDS with XOR-swizzled staging (see comments in loop).
// QF/KF stored in K=32 MFMA fragment order (coalesced 16B/lane in attn):
//   frag f covers dh f*32..f*32+31 of a 16-row tile; lane L holds
//   M[row = tile*16 + (L&15)][dh = f*32 + (L>>4)*8 + j], j=0..7 (16B).
//   Address: (((bh*128+tile)*2+f)*64+L)*8 + j.   Q pre-scaled by 1/8*log2(e).
// VF stored in K=32 PV B-frag order over 32-key groups (kt2 = key>>5):
//   lane (quad,lr), slot j:  key = 32*kt2 + (j<4 ? quad*4+j : 16+quad*4+(j-4)),
//   dh = dt*16+lr.  addr = ((bh*64+kt2)*4+dt)*512 + lane*8 + j.
__global__ __launch_bounds__(256) void qkv_gemm(
    const f16* __restrict__ Xh, const f16* __restrict__ Wh,
    const float* __restrict__ bq, const float* __restrict__ bk,
    const float* __restrict__ bv,
    f16* __restrict__ QF, f16* __restrict__ KF, f16* __restrict__ VF) {
  __shared__ f16 Ah[128 * 64];
  __shared__ f16 Bh[128 * 64];
  const int t = threadIdx.x;
  const int tileM = blockIdx.x * 128;
  const int nGlob = blockIdx.y * 128;
  const int mat = nGlob >> 10;
  const int col0 = nGlob & 1023;
  const int wave = t >> 6, lane = t & 63;
  const int mOff = (wave & 1) * 64, nOff = (wave >> 1) * 64;
  const int lr = lane & 15, quad = lane >> 4;

  f32x4 acc[4][4];
#pragma unroll
  for (int i = 0; i < 4; i++)
#pragma unroll
    for (int j = 0; j < 4; j++) acc[i][j] = f32x4{0.f, 0.f, 0.f, 0.f};

  const int srow = t >> 3;                        // 0..31
  const int sx = ((t & 7) ^ (srow & 7)) * 8;      // f16 offset within row
  const f16* ag = Xh + (size_t)(tileM + srow) * ND + sx;
  const f16* bg = Wh + (size_t)mat * ND * ND + (size_t)(col0 + srow) * ND + sx;
  const bool qk = (mat < 2);
  const int rx = lr & 7;  // row&7 for all frag rows this lane reads

  for (int kk = 0; kk < ND; kk += 64) {
    __syncthreads();
    gl2lds16(ag + kk,                       Ah + t * 8);
    gl2lds16(ag + (size_t)32 * ND + kk,     Ah + 2048 + t * 8);
    gl2lds16(ag + (size_t)64 * ND + kk,     Ah + 4096 + t * 8);
    gl2lds16(ag + (size_t)96 * ND + kk,     Ah + 6144 + t * 8);
    gl2lds16(bg + kk,                       Bh + t * 8);
    gl2lds16(bg + (size_t)32 * ND + kk,     Bh + 2048 + t * 8);
    gl2lds16(bg + (size_t)64 * ND + kk,     Bh + 4096 + t * 8);
    gl2lds16(bg + (size_t)96 * ND + kk,     Bh + 6144 + t * 8);
    __syncthreads();
#pragma unroll
    for (int c = 0; c < 2; c++) {
      const int ch = ((c * 4 + quad) ^ rx) * 8;  // swizzled chunk (f16 units)
      f16x8 af[4], bf[4];
#pragma unroll
      for (int i = 0; i < 4; i++)
        af[i] = *(const f16x8*)(Ah + (mOff + i * 16 + lr) * 64 + ch);
#pragma unroll
      for (int j = 0; j < 4; j++)
        bf[j] = *(const f16x8*)(Bh + (nOff + j * 16 + lr) * 64 + ch);
      if (qk) {
#pragma unroll
        for (int i = 0; i < 4; i++)
#pragma unroll
          for (int j = 0; j < 4; j++)
            acc[i][j] = __builtin_amdgcn_mfma_f32_16x16x32_f16(bf[j], af[i], acc[i][j], 0, 0, 0);
      } else {
#pragma unroll
        for (int i = 0; i < 4; i++)
#pragma unroll
          for (int j = 0; j < 4; j++)
            acc[i][j] = __builtin_amdgcn_mfma_f32_16x16x32_f16(af[i], bf[j], acc[i][j], 0, 0, 0);
      }
    }
  }

  if (qk) {
    const float* bias = (mat == 0) ? bq : bk;
    f16* dst = (mat == 0) ? QF : KF;
    const float sc = (mat == 0) ? 0.18033688f : 1.0f;  // 1/8*log2(e) folded into Q
    const int jstart = (quad & 1) * 4;
#pragma unroll
    for (int j = 0; j < 4; j++) {
      int n0 = col0 + nOff + j * 16;
      int h = n0 >> 6;
      int f = j >> 1;
      int lam = lr + 16 * ((2 * j + (quad >> 1)) & 3);
      float4 bb = *(const float4*)(bias + n0 + quad * 4);
#pragma unroll
      for (int i = 0; i < 4; i++) {
        int sF = tileM + mOff + i * 16;
        int b = sF >> 11, st = (sF & 2047) >> 4;
        int bh = b * NH + h;
        f16x4 v;
#pragma unroll
        for (int r = 0; r < 4; r++) v[r] = (f16)((acc[i][j][r] + (&bb.x)[r]) * sc);
        *(f16x4*)(dst + (((size_t)(bh * 128 + st) * 2 + f) * 64 + lam) * 8 + jstart) = v;
      }
    }
  } else {
#pragma unroll
    for (int j = 0; j < 4; j++) {
      int n = col0 + nOff + j * 16 + lr;
      int h = n >> 6, dt = (n >> 4) & 3;
      float bb = bv[n];
#pragma unroll
      for (int i = 0; i < 4; i++) {
        int sF = tileM + mOff + i * 16;
        int b = sF >> 11;
        int kt2 = (sF & 2047) >> 5;
        int ts = (sF >> 4) & 1;
        int bh = b * NH + h;
        f16x4 v;
#pragma unroll
        for (int r = 0; r < 4; r++) v[r] = (f16)(acc[i][j][r] + bb);
        *(f16x4*)(VF + ((size_t)(bh * 64 + kt2) * 4 + dt) * 512 +
                  (size_t)(quad * 16 + lr) * 8 + 4 * ts) = v;
      }
    }
  }
}

// ---------------- flash attention: LDS K/V + cross-group pipeline ----------
// R5 post-mortem: pipes are MFMA 37 µs / LDS 20 µs / VALU 28 µs but wall was
// 74 µs — the serial QK->exp->PV chain per group left pipes idle at 2
// waves/SIMD (grid-capped).  Fix: software-pipeline ACROSS groups — PV of
// group g-1 is deferred into iteration g, so each iteration issues 36
// mutually-independent MFMAs (16 QK[g] + 20 PV[g-1]) back-to-back, and
// exp[g] runs in their shadow.  Carried state: pfP (P of g-1), vvP (V of
// g-1) in registers.  LDS double-buffer + staging discipline unchanged.
// grid (64,8): xcd = bh&7 -> one bh's q-blocks share one XCD's L2.
__global__ __launch_bounds__(256, 2) void attn_kernel(
    const f16* __restrict__ QF, const f16* __restrict__ KF,
    const f16* __restrict__ VF, float* __restrict__ out) {
  __shared__ f16 LK[2][2048];
  __shared__ f16 LV[2][2048];
  const int t = threadIdx.x, wave = t >> 6, lane = t & 63;
  const int lr = lane & 15, quad = lane >> 4;
  const int bh = blockIdx.x, qb = blockIdx.y;
  const int bb = bh >> 4, hh = bh & 15;
  const size_t bhOff = (size_t)bh * 131072;  // 256 KB of f16 per bh
  const f16* Qp = QF + bhOff + (size_t)lane * 8;
  const f16* Kg = KF + bhOff + (size_t)t * 8;  // staging: thread t -> 16B
  const f16* Vg = VF + bhOff + (size_t)t * 8;
  const int st0 = qb * 16 + wave * 4;  // first of 4 q-tiles for this wave

  // Q B-frags for K=32 (n=q=lane&15, k=dh=(lane>>4)*8+j + f*32), pre-scaled
  f16x8 qf[4][2];
#pragma unroll
  for (int qt = 0; qt < 4; qt++) {
    qf[qt][0] = *(const f16x8*)(Qp + (size_t)(st0 + qt) * 1024);
    qf[qt][1] = *(const f16x8*)(Qp + (size_t)(st0 + qt) * 1024 + 512);
  }

  f32x4 o[4][4];
#pragma unroll
  for (int qt = 0; qt < 4; qt++)
#pragma unroll
    for (int dt = 0; dt < 4; dt++) o[qt][dt] = f32x4{0.f, 0.f, 0.f, 0.f};
  f32x4 lacc[4];
#pragma unroll
  for (int qt = 0; qt < 4; qt++) lacc[qt] = f32x4{0.f, 0.f, 0.f, 0.f};
  const f16x8 ones8 = {(f16)1.f, (f16)1.f, (f16)1.f, (f16)1.f,
                       (f16)1.f, (f16)1.f, (f16)1.f, (f16)1.f};

  // carried pipeline state: P and V of the previous group
  f16x8 pfP[4], vvP[4];

  // ---- prologue: stage group 0, QK[0]+exp[0], stage group 1 ----
  gl2lds16(Kg, &LK[0][t * 8]);
  gl2lds16(Vg, &LV[0][t * 8]);
  __syncthreads();
  {
    f16x8 kk[4];
#pragma unroll
    for (int i = 0; i < 4; i++)
      kk[i] = *(const f16x8*)(&LK[0][i * 512 + lane * 8]);
#pragma unroll
    for (int i = 0; i < 4; i++)
      vvP[i] = *(const f16x8*)(&LV[0][i * 512 + lane * 8]);
    // stage group 1 into buf 1 (in flight during QK[0])
    gl2lds16(Kg + 2048, &LK[1][t * 8]);
    gl2lds16(Vg + 2048, &LV[1][t * 8]);
    f32x4 sA[4], sB[4];
#pragma unroll
    for (int qt = 0; qt < 4; qt++) {
      sA[qt] = f32x4{0.f, 0.f, 0.f, 0.f};
      sA[qt] = __builtin_amdgcn_mfma_f32_16x16x32_f16(kk[0], qf[qt][0], sA[qt], 0, 0, 0);
      sA[qt] = __builtin_amdgcn_mfma_f32_16x16x32_f16(kk[1], qf[qt][1], sA[qt], 0, 0, 0);
      sB[qt] = f32x4{0.f, 0.f, 0.f, 0.f};
      sB[qt] = __builtin_amdgcn_mfma_f32_16x16x32_f16(kk[2], qf[qt][0], sB[qt], 0, 0, 0);
      sB[qt] = __builtin_amdgcn_mfma_f32_16x16x32_f16(kk[3], qf[qt][1], sB[qt], 0, 0, 0);
    }
#pragma unroll
    for (int qt = 0; qt < 4; qt++) {
      f16x2 a0 = pk_f16(fast_exp2(sA[qt][0]), fast_exp2(sA[qt][1]));
      f16x2 a1 = pk_f16(fast_exp2(sA[qt][2]), fast_exp2(sA[qt][3]));
      f16x2 b0 = pk_f16(fast_exp2(sB[qt][0]), fast_exp2(sB[qt][1]));
      f16x2 b1 = pk_f16(fast_exp2(sB[qt][2]), fast_exp2(sB[qt][3]));
      f16x4 lo = __builtin_shufflevector(a0, a1, 0, 1, 2, 3);
      f16x4 hi = __builtin_shufflevector(b0, b1, 0, 1, 2, 3);
      pfP[qt] = __builtin_shufflevector(lo, hi, 0, 1, 2, 3, 4, 5, 6, 7);
    }
  }
  __syncthreads();  // buf1 staged; all waves done with buf0 LDS reads

  for (int g = 1; g < 64; ++g) {
    const int buf = g & 1;
    // read group g fragments (linear 16B/lane, conflict-free)
    f16x8 kk[4], vv[4];
#pragma unroll
    for (int i = 0; i < 4; i++)
      kk[i] = *(const f16x8*)(&LK[buf][i * 512 + lane * 8]);
#pragma unroll
    for (int i = 0; i < 4; i++)
      vv[i] = *(const f16x8*)(&LV[buf][i * 512 + lane * 8]);
    // stage group g+1 over buf of g-1 (its LDS reads finished last iter)
    if (g < 63) {
      const size_t nk = (size_t)(g + 1) * 2048;
      gl2lds16(Kg + nk, &LK[buf ^ 1][t * 8]);
      gl2lds16(Vg + nk, &LV[buf ^ 1][t * 8]);
    }
    // ---- 36 independent MFMAs: QK[g] (fresh kk) + PV[g-1] (carried) ----
    f32x4 sA[4], sB[4];
#pragma unroll
    for (int qt = 0; qt < 4; qt++) {
      sA[qt] = f32x4{0.f, 0.f, 0.f, 0.f};
      sA[qt] = __builtin_amdgcn_mfma_f32_16x16x32_f16(kk[0], qf[qt][0], sA[qt], 0, 0, 0);
      sA[qt] = __builtin_amdgcn_mfma_f32_16x16x32_f16(kk[1], qf[qt][1], sA[qt], 0, 0, 0);
      sB[qt] = f32x4{0.f, 0.f, 0.f, 0.f};
      sB[qt] = __builtin_amdgcn_mfma_f32_16x16x32_f16(kk[2], qf[qt][0], sB[qt], 0, 0, 0);
      sB[qt] = __builtin_amdgcn_mfma_f32_16x16x32_f16(kk[3], qf[qt][1], sB[qt], 0, 0, 0);
    }
#pragma unroll
    for (int dt = 0; dt < 4; dt++)
#pragma unroll
      for (int qt = 0; qt < 4; qt++)
        o[qt][dt] = __builtin_amdgcn_mfma_f32_16x16x32_f16(pfP[qt], vvP[dt], o[qt][dt], 0, 0, 0);
#pragma unroll
    for (int qt = 0; qt < 4; qt++)
      lacc[qt] = __builtin_amdgcn_mfma_f32_16x16x32_f16(pfP[qt], ones8, lacc[qt], 0, 0, 0);
    // ---- exp[g] + pack -> carried state (in MFMA shadow) ----
#pragma unroll
    for (int qt = 0; qt < 4; qt++) {
      f16x2 a0 = pk_f16(fast_exp2(sA[qt][0]), fast_exp2(sA[qt][1]));
      f16x2 a1 = pk_f16(fast_exp2(sA[qt][2]), fast_exp2(sA[qt][3]));
      f16x2 b0 = pk_f16(fast_exp2(sB[qt][0]), fast_exp2(sB[qt][1]));
      f16x2 b1 = pk_f16(fast_exp2(sB[qt][2]), fast_exp2(sB[qt][3]));
      f16x4 lo = __builtin_shufflevector(a0, a1, 0, 1, 2, 3);
      f16x4 hi = __builtin_shufflevector(b0, b1, 0, 1, 2, 3);
      pfP[qt] = __builtin_shufflevector(lo, hi, 0, 1, 2, 3, 4, 5, 6, 7);
    }
#pragma unroll
    for (int i = 0; i < 4; i++) vvP[i] = vv[i];
    // barrier: next-group staging complete + all waves done reading buf
    __syncthreads();
  }

  // ---- epilogue: PV[63] ----
#pragma unroll
  for (int dt = 0; dt < 4; dt++)
#pragma unroll
    for (int qt = 0; qt < 4; qt++)
      o[qt][dt] = __builtin_amdgcn_mfma_f32_16x16x32_f16(pfP[qt], vvP[dt], o[qt][dt], 0, 0, 0);
#pragma unroll
  for (int qt = 0; qt < 4; qt++)
    lacc[qt] = __builtin_amdgcn_mfma_f32_16x16x32_f16(pfP[qt], ones8, lacc[qt], 0, 0, 0);

  // lacc C-layout: lane holds q=quad*4+r (all cols equal) -> no shuffles
#pragma unroll
  for (int qt = 0; qt < 4; qt++) {
#pragma unroll
    for (int r = 0; r < 4; r++) {
      float inv = 1.0f / lacc[qt][r];
      int q = qb * 256 + wave * 64 + qt * 16 + quad * 4 + r;
#pragma unroll
      for (int dt = 0; dt < 4; dt++)
        out[((size_t)bb * NS + q) * ND + hh * 64 + dt * 16 + lr] = o[qt][dt][r] * inv;
    }
  }
}

extern "C" void kernel_launch(void* const* d_in, const int* in_sizes, int n_in,
                              void* d_out, int out_size, void* d_ws, size_t ws_size,
                              hipStream_t stream) {
  const float* X  = (const float*)d_in[0];
  const float* Wq = (const float*)d_in[1];
  const float* bq = (const float*)d_in[2];
  const float* Wk = (const float*)d_in[3];
  const float* bk = (const float*)d_in[4];
  const float* Wv = (const float*)d_in[5];
  const float* bv = (const float*)d_in[6];
  float* out = (float*)d_out;

  // ws: Xh 16MB | Wh 6MB | QF 16MB | KF 16MB | VF 16MB = 70MB
  f16* Xh = (f16*)d_ws;
  f16* Wh = (f16*)((char*)d_ws + (size_t)(16u << 20));
  f16* QF = (f16*)((char*)d_ws + (size_t)(22u << 20));
  f16* KF = (f16*)((char*)d_ws + (size_t)(38u << 20));
  f16* VF = (f16*)((char*)d_ws + (size_t)(54u << 20));

  cvt_all<<<11264, 256, 0, stream>>>(X, Wq, Wk, Wv, Xh, Wh);
  qkv_gemm<<<dim3(64, 24), 256, 0, stream>>>(Xh, Wh, bq, bk, bv, QF, KF, VF);
  attn_kernel<<<dim3(64, 8), 256, 0, stream>>>(QF, KF, VF, out);
}

// Round 7
// 214.038 us; speedup vs baseline: 1.3232x; 1.0090x over previous
//
#include <hip/hip_runtime.h>

typedef _Float16 f16;
typedef f16 f16x2 __attribute__((ext_vector_type(2)));
typedef f16 f16x4 __attribute__((ext_vector_type(4)));
typedef f16 f16x8 __attribute__((ext_vector_type(8)));
typedef float f32x4 __attribute__((ext_vector_type(4)));

#define NB 4
#define NS 2048
#define ND 1024
#define NH 16
#define NDH 64

__device__ __forceinline__ void gl2lds16(const void* g, void* l) {
  __builtin_amdgcn_global_load_lds(
      (const __attribute__((address_space(1))) unsigned int*)g,
      (__attribute__((address_space(3))) unsigned int*)l, 16, 0, 0);
}

__device__ __forceinline__ float fast_exp2(float x) {
  return __builtin_amdgcn_exp2f(x);  // v_exp_f32
}

__device__ __forceinline__ f16x2 pk_f16(float a, float b) {
  return __builtin_bit_cast(f16x2, __builtin_amdgcn_cvt_pkrtz(a, b));  // v_cvt_pkrtz_f16_f32
}

// ---------------- fp32 -> f16 conversion (all 4 inputs, one launch) ----------
__global__ __launch_bounds__(256) void cvt_all(
    const float* __restrict__ X, const float* __restrict__ Wq,
    const float* __restrict__ Wk, const float* __restrict__ Wv,
    f16* __restrict__ Xh, f16* __restrict__ Wh) {
  int b = blockIdx.x;
  const float* src;
  f16* dst;
  int off;
  if (b < 8192)       { src = X;  dst = Xh;               off = 0; }
  else if (b < 9216)  { src = Wq; dst = Wh;               off = 8192; }
  else if (b < 10240) { src = Wk; dst = Wh + (1u << 20);  off = 9216; }
  else                { src = Wv; dst = Wh + (2u << 20);  off = 10240; }
  int i = (b - off) * 256 + threadIdx.x;
  float4 v = ((const float4*)src)[i];
  f16x4 h = {(f16)v.x, (f16)v.y, (f16)v.z, (f16)v.w};
  ((f16x4*)dst)[i] = h;
}

// ---------------- fused QKV projection GEMM (unchanged) ----------------
// BK=64, single-buffered LDS with XOR-swizzled staging (see comments in loop).
// QF/KF stored in K=32 MFMA fragment order (coalesced 16B/lane in attn):
//   frag f covers dh f*32..f*32+31 of a 16-row tile; lane L holds
//   M[row = tile*16 + (L&15)][dh = f*32 + (L>>4)*8 + j], j=0..7 (16B).
//   Address: (((bh*128+tile)*2+f)*64+L)*8 + j.   Q pre-scaled by 1/8*log2(e).
// VF stored in K=32 PV B-frag order over 32-key groups (kt2 = key>>5):
//   lane (quad,lr), slot j:  key = 32*kt2 + (j<4 ? quad*4+j : 16+quad*4+(j-4)),
//   dh = dt*16+lr.  addr = ((bh*64+kt2)*4+dt)*512 + lane*8 + j.
__global__ __launch_bounds__(256) void qkv_gemm(
    const f16* __restrict__ Xh, const f16* __restrict__ Wh,
    const float* __restrict__ bq, const float* __restrict__ bk,
    const float* __restrict__ bv,
    f16* __restrict__ QF, f16* __restrict__ KF, f16* __restrict__ VF) {
  __shared__ f16 Ah[128 * 64];
  __shared__ f16 Bh[128 * 64];
  const int t = threadIdx.x;
  const int tileM = blockIdx.x * 128;
  const int nGlob = blockIdx.y * 128;
  const int mat = nGlob >> 10;
  const int col0 = nGlob & 1023;
  const int wave = t >> 6, lane = t & 63;
  const int mOff = (wave & 1) * 64, nOff = (wave >> 1) * 64;
  const int lr = lane & 15, quad = lane >> 4;

  f32x4 acc[4][4];
#pragma unroll
  for (int i = 0; i < 4; i++)
#pragma unroll
    for (int j = 0; j < 4; j++) acc[i][j] = f32x4{0.f, 0.f, 0.f, 0.f};

  const int srow = t >> 3;                        // 0..31
  const int sx = ((t & 7) ^ (srow & 7)) * 8;      // f16 offset within row
  const f16* ag = Xh + (size_t)(tileM + srow) * ND + sx;
  const f16* bg = Wh + (size_t)mat * ND * ND + (size_t)(col0 + srow) * ND + sx;
  const bool qk = (mat < 2);
  const int rx = lr & 7;  // row&7 for all frag rows this lane reads

  for (int kk = 0; kk < ND; kk += 64) {
    __syncthreads();
    gl2lds16(ag + kk,                       Ah + t * 8);
    gl2lds16(ag + (size_t)32 * ND + kk,     Ah + 2048 + t * 8);
    gl2lds16(ag + (size_t)64 * ND + kk,     Ah + 4096 + t * 8);
    gl2lds16(ag + (size_t)96 * ND + kk,     Ah + 6144 + t * 8);
    gl2lds16(bg + kk,                       Bh + t * 8);
    gl2lds16(bg + (size_t)32 * ND + kk,     Bh + 2048 + t * 8);
    gl2lds16(bg + (size_t)64 * ND + kk,     Bh + 4096 + t * 8);
    gl2lds16(bg + (size_t)96 * ND + kk,     Bh + 6144 + t * 8);
    __syncthreads();
#pragma unroll
    for (int c = 0; c < 2; c++) {
      const int ch = ((c * 4 + quad) ^ rx) * 8;  // swizzled chunk (f16 units)
      f16x8 af[4], bf[4];
#pragma unroll
      for (int i = 0; i < 4; i++)
        af[i] = *(const f16x8*)(Ah + (mOff + i * 16 + lr) * 64 + ch);
#pragma unroll
      for (int j = 0; j < 4; j++)
        bf[j] = *(const f16x8*)(Bh + (nOff + j * 16 + lr) * 64 + ch);
      if (qk) {
#pragma unroll
        for (int i = 0; i < 4; i++)
#pragma unroll
          for (int j = 0; j < 4; j++)
            acc[i][j] = __builtin_amdgcn_mfma_f32_16x16x32_f16(bf[j], af[i], acc[i][j], 0, 0, 0);
      } else {
#pragma unroll
        for (int i = 0; i < 4; i++)
#pragma unroll
          for (int j = 0; j < 4; j++)
            acc[i][j] = __builtin_amdgcn_mfma_f32_16x16x32_f16(af[i], bf[j], acc[i][j], 0, 0, 0);
      }
    }
  }

  if (qk) {
    const float* bias = (mat == 0) ? bq : bk;
    f16* dst = (mat == 0) ? QF : KF;
    const float sc = (mat == 0) ? 0.18033688f : 1.0f;  // 1/8*log2(e) folded into Q
    const int jstart = (quad & 1) * 4;
#pragma unroll
    for (int j = 0; j < 4; j++) {
      int n0 = col0 + nOff + j * 16;
      int h = n0 >> 6;
      int f = j >> 1;
      int lam = lr + 16 * ((2 * j + (quad >> 1)) & 3);
      float4 bb = *(const float4*)(bias + n0 + quad * 4);
#pragma unroll
      for (int i = 0; i < 4; i++) {
        int sF = tileM + mOff + i * 16;
        int b = sF >> 11, st = (sF & 2047) >> 4;
        int bh = b * NH + h;
        f16x4 v;
#pragma unroll
        for (int r = 0; r < 4; r++) v[r] = (f16)((acc[i][j][r] + (&bb.x)[r]) * sc);
        *(f16x4*)(dst + (((size_t)(bh * 128 + st) * 2 + f) * 64 + lam) * 8 + jstart) = v;
      }
    }
  } else {
#pragma unroll
    for (int j = 0; j < 4; j++) {
      int n = col0 + nOff + j * 16 + lr;
      int h = n >> 6, dt = (n >> 4) & 3;
      float bb = bv[n];
#pragma unroll
      for (int i = 0; i < 4; i++) {
        int sF = tileM + mOff + i * 16;
        int b = sF >> 11;
        int kt2 = (sF & 2047) >> 5;
        int ts = (sF >> 4) & 1;
        int bh = b * NH + h;
        f16x4 v;
#pragma unroll
        for (int r = 0; r < 4; r++) v[r] = (f16)(acc[i][j][r] + bb);
        *(f16x4*)(VF + ((size_t)(bh * 64 + kt2) * 4 + dt) * 512 +
                  (size_t)(quad * 16 + lr) * 8 + 4 * ts) = v;
      }
    }
  }
}

// ------- flash attention: LDS K/V ring + counted-vmcnt barriers (T4+T5) -----
// R6 post-mortem: cross-group MFMA pipelining alone was +3 µs; the residual
// stall is __syncthreads' implicit s_waitcnt vmcnt(0) draining the
// global_load_lds queue every iteration (distance-1 prefetch can't span a
// barrier).  Fix: 3-buffer LDS ring with distance-2 prefetch + raw s_barrier
// preceded by s_waitcnt vmcnt(2) — the 2 staging loads issued THIS iteration
// stay in flight across the barrier; only last iteration's must land.
// Race audit: buf[(g+2)%3] written at iter g was last read at iter g-1;
// barrier(g-1) orders those reads before any iter-g staging issue; staging(g)
// completion is enforced by vmcnt(2) at barrier(g+1), one iter before its
// reads at g+2.  Same-iter read/write buffers distinct mod 3.
// PV[g-1] (register-only, carried pfP/vvP) issues BEFORE QK[g] (ds-dependent)
// so the MFMA pipe starts during lgkmcnt resolution; s_setprio(1) wraps the
// 36-MFMA cluster (T5).  grid (64,8): xcd = bh&7 (one bh per XCD's L2).
__global__ __launch_bounds__(256, 2) void attn_kernel(
    const f16* __restrict__ QF, const f16* __restrict__ KF,
    const f16* __restrict__ VF, float* __restrict__ out) {
  __shared__ f16 LK[3][2048];
  __shared__ f16 LV[3][2048];
  const int t = threadIdx.x, wave = t >> 6, lane = t & 63;
  const int lr = lane & 15, quad = lane >> 4;
  const int bh = blockIdx.x, qb = blockIdx.y;
  const int bb = bh >> 4, hh = bh & 15;
  const size_t bhOff = (size_t)bh * 131072;  // 256 KB of f16 per bh
  const f16* Qp = QF + bhOff + (size_t)lane * 8;
  const f16* Kg = KF + bhOff + (size_t)t * 8;  // staging: thread t -> 16B
  const f16* Vg = VF + bhOff + (size_t)t * 8;
  const int st0 = qb * 16 + wave * 4;  // first of 4 q-tiles for this wave

  // Q B-frags for K=32 (n=q=lane&15, k=dh=(lane>>4)*8+j + f*32), pre-scaled
  f16x8 qf[4][2];
#pragma unroll
  for (int qt = 0; qt < 4; qt++) {
    qf[qt][0] = *(const f16x8*)(Qp + (size_t)(st0 + qt) * 1024);
    qf[qt][1] = *(const f16x8*)(Qp + (size_t)(st0 + qt) * 1024 + 512);
  }

  f32x4 o[4][4];
#pragma unroll
  for (int qt = 0; qt < 4; qt++)
#pragma unroll
    for (int dt = 0; dt < 4; dt++) o[qt][dt] = f32x4{0.f, 0.f, 0.f, 0.f};
  f32x4 lacc[4];
#pragma unroll
  for (int qt = 0; qt < 4; qt++) lacc[qt] = f32x4{0.f, 0.f, 0.f, 0.f};
  const f16x8 ones8 = {(f16)1.f, (f16)1.f, (f16)1.f, (f16)1.f,
                       (f16)1.f, (f16)1.f, (f16)1.f, (f16)1.f};

  // carried pipeline state: P and V of the previous group
  f16x8 pfP[4], vvP[4];

  // ---- prologue: stage groups 0,1; wait group 0 only (vmcnt(2)) ----
  gl2lds16(Kg,        &LK[0][t * 8]);
  gl2lds16(Vg,        &LV[0][t * 8]);
  gl2lds16(Kg + 2048, &LK[1][t * 8]);
  gl2lds16(Vg + 2048, &LV[1][t * 8]);
  asm volatile("s_waitcnt vmcnt(2)" ::: "memory");
  __builtin_amdgcn_s_barrier();

  // ---- peeled g = 0: QK[0] + exp[0]; stage group 2 ----
  {
    f16x8 kk[4];
#pragma unroll
    for (int i = 0; i < 4; i++)
      kk[i] = *(const f16x8*)(&LK[0][i * 512 + lane * 8]);
#pragma unroll
    for (int i = 0; i < 4; i++)
      vvP[i] = *(const f16x8*)(&LV[0][i * 512 + lane * 8]);
    gl2lds16(Kg + 2 * 2048, &LK[2][t * 8]);
    gl2lds16(Vg + 2 * 2048, &LV[2][t * 8]);
    f32x4 sA[4], sB[4];
#pragma unroll
    for (int qt = 0; qt < 4; qt++) {
      sA[qt] = f32x4{0.f, 0.f, 0.f, 0.f};
      sA[qt] = __builtin_amdgcn_mfma_f32_16x16x32_f16(kk[0], qf[qt][0], sA[qt], 0, 0, 0);
      sA[qt] = __builtin_amdgcn_mfma_f32_16x16x32_f16(kk[1], qf[qt][1], sA[qt], 0, 0, 0);
      sB[qt] = f32x4{0.f, 0.f, 0.f, 0.f};
      sB[qt] = __builtin_amdgcn_mfma_f32_16x16x32_f16(kk[2], qf[qt][0], sB[qt], 0, 0, 0);
      sB[qt] = __builtin_amdgcn_mfma_f32_16x16x32_f16(kk[3], qf[qt][1], sB[qt], 0, 0, 0);
    }
#pragma unroll
    for (int qt = 0; qt < 4; qt++) {
      f16x2 a0 = pk_f16(fast_exp2(sA[qt][0]), fast_exp2(sA[qt][1]));
      f16x2 a1 = pk_f16(fast_exp2(sA[qt][2]), fast_exp2(sA[qt][3]));
      f16x2 b0 = pk_f16(fast_exp2(sB[qt][0]), fast_exp2(sB[qt][1]));
      f16x2 b1 = pk_f16(fast_exp2(sB[qt][2]), fast_exp2(sB[qt][3]));
      f16x4 lo = __builtin_shufflevector(a0, a1, 0, 1, 2, 3);
      f16x4 hi = __builtin_shufflevector(b0, b1, 0, 1, 2, 3);
      pfP[qt] = __builtin_shufflevector(lo, hi, 0, 1, 2, 3, 4, 5, 6, 7);
    }
  }
  asm volatile("s_waitcnt vmcnt(2)" ::: "memory");  // group-1 loads landed
  __builtin_amdgcn_s_barrier();

  int cur = 1;  // g % 3
  for (int g = 1; g < 64; ++g) {
    // read group g fragments (linear 16B/lane, conflict-free)
    f16x8 kk[4], vv[4];
#pragma unroll
    for (int i = 0; i < 4; i++)
      kk[i] = *(const f16x8*)(&LK[cur][i * 512 + lane * 8]);
#pragma unroll
    for (int i = 0; i < 4; i++)
      vv[i] = *(const f16x8*)(&LV[cur][i * 512 + lane * 8]);
    // stage group (g+2)&63 into buf (g+2)%3 (wrap staging: harmless, no branch)
    {
      int s2 = cur + 2; if (s2 >= 3) s2 -= 3;
      const size_t nk = (size_t)((g + 2) & 63) * 2048;
      gl2lds16(Kg + nk, &LK[s2][t * 8]);
      gl2lds16(Vg + nk, &LV[s2][t * 8]);
    }
    // ---- 36 independent MFMAs: PV[g-1] (carried, reg-only) then QK[g] ----
    __builtin_amdgcn_s_setprio(1);
#pragma unroll
    for (int dt = 0; dt < 4; dt++)
#pragma unroll
      for (int qt = 0; qt < 4; qt++)
        o[qt][dt] = __builtin_amdgcn_mfma_f32_16x16x32_f16(pfP[qt], vvP[dt], o[qt][dt], 0, 0, 0);
#pragma unroll
    for (int qt = 0; qt < 4; qt++)
      lacc[qt] = __builtin_amdgcn_mfma_f32_16x16x32_f16(pfP[qt], ones8, lacc[qt], 0, 0, 0);
    f32x4 sA[4], sB[4];
#pragma unroll
    for (int qt = 0; qt < 4; qt++) {
      sA[qt] = f32x4{0.f, 0.f, 0.f, 0.f};
      sA[qt] = __builtin_amdgcn_mfma_f32_16x16x32_f16(kk[0], qf[qt][0], sA[qt], 0, 0, 0);
      sA[qt] = __builtin_amdgcn_mfma_f32_16x16x32_f16(kk[1], qf[qt][1], sA[qt], 0, 0, 0);
      sB[qt] = f32x4{0.f, 0.f, 0.f, 0.f};
      sB[qt] = __builtin_amdgcn_mfma_f32_16x16x32_f16(kk[2], qf[qt][0], sB[qt], 0, 0, 0);
      sB[qt] = __builtin_amdgcn_mfma_f32_16x16x32_f16(kk[3], qf[qt][1], sB[qt], 0, 0, 0);
    }
    __builtin_amdgcn_s_setprio(0);
    // ---- exp[g] + pack -> carried state (in MFMA shadow) ----
#pragma unroll
    for (int qt = 0; qt < 4; qt++) {
      f16x2 a0 = pk_f16(fast_exp2(sA[qt][0]), fast_exp2(sA[qt][1]));
      f16x2 a1 = pk_f16(fast_exp2(sA[qt][2]), fast_exp2(sA[qt][3]));
      f16x2 b0 = pk_f16(fast_exp2(sB[qt][0]), fast_exp2(sB[qt][1]));
      f16x2 b1 = pk_f16(fast_exp2(sB[qt][2]), fast_exp2(sB[qt][3]));
      f16x4 lo = __builtin_shufflevector(a0, a1, 0, 1, 2, 3);
      f16x4 hi = __builtin_shufflevector(b0, b1, 0, 1, 2, 3);
      pfP[qt] = __builtin_shufflevector(lo, hi, 0, 1, 2, 3, 4, 5, 6, 7);
    }
#pragma unroll
    for (int i = 0; i < 4; i++) vvP[i] = vv[i];
    // counted barrier: this iter's 2 staging loads stay in flight
    asm volatile("s_waitcnt vmcnt(2)" ::: "memory");
    __builtin_amdgcn_s_barrier();
    cur = (cur == 2) ? 0 : cur + 1;
  }

  // ---- epilogue: PV[63] ----
#pragma unroll
  for (int dt = 0; dt < 4; dt++)
#pragma unroll
    for (int qt = 0; qt < 4; qt++)
      o[qt][dt] = __builtin_amdgcn_mfma_f32_16x16x32_f16(pfP[qt], vvP[dt], o[qt][dt], 0, 0, 0);
#pragma unroll
  for (int qt = 0; qt < 4; qt++)
    lacc[qt] = __builtin_amdgcn_mfma_f32_16x16x32_f16(pfP[qt], ones8, lacc[qt], 0, 0, 0);

  // lacc C-layout: lane holds q=quad*4+r (all cols equal) -> no shuffles
#pragma unroll
  for (int qt = 0; qt < 4; qt++) {
#pragma unroll
    for (int r = 0; r < 4; r++) {
      float inv = 1.0f / lacc[qt][r];
      int q = qb * 256 + wave * 64 + qt * 16 + quad * 4 + r;
#pragma unroll
      for (int dt = 0; dt < 4; dt++)
        out[((size_t)bb * NS + q) * ND + hh * 64 + dt * 16 + lr] = o[qt][dt][r] * inv;
    }
  }
}

extern "C" void kernel_launch(void* const* d_in, const int* in_sizes, int n_in,
                              void* d_out, int out_size, void* d_ws, size_t ws_size,
                              hipStream_t stream) {
  const float* X  = (const float*)d_in[0];
  const float* Wq = (const float*)d_in[1];
  const float* bq = (const float*)d_in[2];
  const float* Wk = (const float*)d_in[3];
  const float* bk = (const float*)d_in[4];
  const float* Wv = (const float*)d_in[5];
  const float* bv = (const float*)d_in[6];
  float* out = (float*)d_out;

  // ws: Xh 16MB | Wh 6MB | QF 16MB | KF 16MB | VF 16MB = 70MB
  f16* Xh = (f16*)d_ws;
  f16* Wh = (f16*)((char*)d_ws + (size_t)(16u << 20));
  f16* QF = (f16*)((char*)d_ws + (size_t)(22u << 20));
  f16* KF = (f16*)((char*)d_ws + (size_t)(38u << 20));
  f16* VF = (f16*)((char*)d_ws + (size_t)(54u << 20));

  cvt_all<<<11264, 256, 0, stream>>>(X, Wq, Wk, Wv, Xh, Wh);
  qkv_gemm<<<dim3(64, 24), 256, 0, stream>>>(Xh, Wh, bq, bk, bv, QF, KF, VF);
  attn_kernel<<<dim3(64, 8), 256, 0, stream>>>(QF, KF, VF, out);
}